// Round 1
// baseline (1376.616 us; speedup 1.0000x reference)
//
#include <hip/hip_runtime.h>
#include <hip/hip_fp16.h>

#define VTGT 32000
#define EDIM 256
#define HDIM 256
#define BATCH 64
#define SLEN 48
#define TLEN 32
#define G3 768

typedef _Float16 f16x2 __attribute__((ext_vector_type(2)));
typedef _Float16 f16x4 __attribute__((ext_vector_type(4)));
typedef _Float16 f16x8 __attribute__((ext_vector_type(8)));
typedef float    f32x4 __attribute__((ext_vector_type(4)));

__device__ __forceinline__ float sigf(float x) { return 1.f / (1.f + __expf(-x)); }
__device__ __forceinline__ float tanhfast(float x) {
    x = fminf(15.f, fmaxf(-15.f, x));
    float e = __expf(2.f * x);
    return (e - 1.f) / (e + 1.f);
}

// ---------------- pack fp32 -> fp16 (vectorized x4) ----------------
__global__ void pack_f16_v4(const float4* __restrict__ s, f16x4* __restrict__ d, int n4) {
    int i = blockIdx.x * blockDim.x + threadIdx.x;
    if (i < n4) {
        float4 v = s[i];
        f16x4 o;
        o[0] = (_Float16)v.x; o[1] = (_Float16)v.y;
        o[2] = (_Float16)v.z; o[3] = (_Float16)v.w;
        d[i] = o;
    }
}

// ---------------- xg = emb[tok] @ Wih^T + bih (fp32) ----------------
// 320 blocks: 0..191 encoder (3072 rows), 192..319 decoder (2048 rows). 16 rows/block.
__global__ __launch_bounds__(256) void xg_kernel(
    const int* __restrict__ src, const int* __restrict__ trg,
    const float* __restrict__ eemb, const float* __restrict__ eWih, const float* __restrict__ ebih,
    const float* __restrict__ demb, const float* __restrict__ dWih, const float* __restrict__ dbih,
    float* __restrict__ xgE, float* __restrict__ xgD)
{
    __shared__ __align__(16) float es[16][EDIM];
    __shared__ int toks[16];
    const int t = threadIdx.x;
    const int blk = blockIdx.x;
    const bool enc = blk < 192;
    const int row0 = enc ? blk * 16 : (blk - 192) * 16;
    if (t < 16) {
        int r = row0 + t;
        int tok;
        if (enc) { int bb = r / SLEN, tt = r % SLEN; tok = src[bb * SLEN + tt]; }
        else     { int bb = r / TLEN, tt = r % TLEN; tok = (tt == 0) ? 1 : trg[bb * TLEN + tt - 1]; }
        toks[t] = tok;
    }
    __syncthreads();
    const float* emb = enc ? eemb : demb;
    const float* Wih = enc ? eWih : dWih;
    const float* bih = enc ? ebih : dbih;
    float* outp = enc ? xgE : xgD;

    for (int i = 0; i < 4; i++) {
        int idx = i * 256 + t;
        int r = idx >> 6, c4 = idx & 63;
        ((float4*)es[r])[c4] = ((const float4*)(emb + (size_t)toks[r] * EDIM))[c4];
    }
    __syncthreads();

    float acc0[16], acc1[16], acc2[16];
#pragma unroll
    for (int r = 0; r < 16; r++) { acc0[r] = 0.f; acc1[r] = 0.f; acc2[r] = 0.f; }
    const float4* w0 = (const float4*)(Wih + (size_t)t * EDIM);
    const float4* w1 = (const float4*)(Wih + (size_t)(t + 256) * EDIM);
    const float4* w2 = (const float4*)(Wih + (size_t)(t + 512) * EDIM);
    for (int e4 = 0; e4 < 64; e4++) {
        float4 a = w0[e4], bq = w1[e4], c = w2[e4];
#pragma unroll
        for (int r = 0; r < 16; r++) {
            float4 hv = ((const float4*)es[r])[e4];
            acc0[r] += a.x * hv.x + a.y * hv.y + a.z * hv.z + a.w * hv.w;
            acc1[r] += bq.x * hv.x + bq.y * hv.y + bq.z * hv.z + bq.w * hv.w;
            acc2[r] += c.x * hv.x + c.y * hv.y + c.z * hv.z + c.w * hv.w;
        }
    }
    float b0 = bih[t], b1 = bih[t + 256], b2 = bih[t + 512];
    for (int r = 0; r < 16; r++) {
        size_t o = (size_t)(row0 + r) * G3;
        outp[o + t]       = acc0[r] + b0;
        outp[o + t + 256] = acc1[r] + b1;
        outp[o + t + 512] = acc2[r] + b2;
    }
}

// ---------------- fp16 dot helpers ----------------
__device__ __forceinline__ float dot8(float4 w, float4 h, float acc) {
    union { float4 f; f16x2 h2[4]; } uw, uh;
    uw.f = w; uh.f = h;
#if __has_builtin(__builtin_amdgcn_fdot2)
#pragma unroll
    for (int i = 0; i < 4; i++)
        acc = __builtin_amdgcn_fdot2(uw.h2[i], uh.h2[i], acc, false);
#else
#pragma unroll
    for (int i = 0; i < 4; i++) {
        acc += (float)uw.h2[i][0] * (float)uh.h2[i][0];
        acc += (float)uw.h2[i][1] * (float)uh.h2[i][1];
    }
#endif
    return acc;
}

// ---------------- GRU recurrence: 64 blocks (one batch element each) ----------------
// Whh streamed from L2 as fp16; h in LDS as fp16; gate math fp32.
__global__ __launch_bounds__(256) void gru_kernel(
    const __half* __restrict__ WhhE, const float* __restrict__ bhhE, const float* __restrict__ xgE,
    const __half* __restrict__ WhhD, const float* __restrict__ bhhD, const float* __restrict__ xgD,
    __half* __restrict__ dech)
{
    __shared__ __align__(16) __half hs[HDIM];
    const int b = blockIdx.x, j = threadIdx.x;
    float h = 0.f;
    hs[j] = (__half)0.f;
    __syncthreads();

    // encoder
    {
        const float4* w0 = (const float4*)(WhhE + (size_t)j * HDIM);
        const float4* w1 = (const float4*)(WhhE + (size_t)(j + 256) * HDIM);
        const float4* w2 = (const float4*)(WhhE + (size_t)(j + 512) * HDIM);
        const float bR = bhhE[j], bZ = bhhE[j + 256], bN = bhhE[j + 512];
        for (int t = 0; t < SLEN; t++) {
            float a0 = 0.f, a1 = 0.f, a2 = 0.f;
            const float4* hp = (const float4*)hs;
#pragma unroll 4
            for (int k = 0; k < 32; k++) {
                float4 hv = hp[k];
                a0 = dot8(w0[k], hv, a0);
                a1 = dot8(w1[k], hv, a1);
                a2 = dot8(w2[k], hv, a2);
            }
            const float* xg = xgE + ((size_t)b * SLEN + t) * G3;
            float r = sigf(xg[j] + a0 + bR);
            float z = sigf(xg[j + 256] + a1 + bZ);
            float n = tanhfast(xg[j + 512] + r * (a2 + bN));
            h = (1.f - z) * n + z * h;
            __syncthreads();
            hs[j] = (__half)h;
            __syncthreads();
        }
    }
    // decoder
    {
        const float4* w0 = (const float4*)(WhhD + (size_t)j * HDIM);
        const float4* w1 = (const float4*)(WhhD + (size_t)(j + 256) * HDIM);
        const float4* w2 = (const float4*)(WhhD + (size_t)(j + 512) * HDIM);
        const float bR = bhhD[j], bZ = bhhD[j + 256], bN = bhhD[j + 512];
        for (int t = 0; t < TLEN; t++) {
            float a0 = 0.f, a1 = 0.f, a2 = 0.f;
            const float4* hp = (const float4*)hs;
#pragma unroll 4
            for (int k = 0; k < 32; k++) {
                float4 hv = hp[k];
                a0 = dot8(w0[k], hv, a0);
                a1 = dot8(w1[k], hv, a1);
                a2 = dot8(w2[k], hv, a2);
            }
            const float* xg = xgD + ((size_t)b * TLEN + t) * G3;
            float r = sigf(xg[j] + a0 + bR);
            float z = sigf(xg[j + 256] + a1 + bZ);
            float n = tanhfast(xg[j + 512] + r * (a2 + bN));
            h = (1.f - z) * n + z * h;
            __syncthreads();
            __half hh = (__half)h;
            hs[j] = hh;
            dech[((size_t)b * TLEN + t) * HDIM + j] = hh;
            __syncthreads();
        }
    }
}

// ---------------- FC: [2048,256] x [256,32000] fp16 MFMA, fp32 accum + bias ----------------
#define KP 136  // LDS pitch in halfs (16B-aligned rows, bank step 4 -> conflict-free-ish)
__global__ __launch_bounds__(256) void fc_kernel(
    const __half* __restrict__ A, const __half* __restrict__ Bw,
    const float* __restrict__ bias, float* __restrict__ out)
{
    __shared__ __align__(16) __half Bs[128 * KP];
    const int nb = blockIdx.x;  // 0..249, 128 vocab cols
    const int mb = blockIdx.y;  // 0..15, 128 rows
    const int tid = threadIdx.x;
    const int wave = tid >> 6, lane = tid & 63;
    const int l15 = lane & 15, q = lane >> 4;

    // A fragments in registers: wave handles m-frags 2*wave, 2*wave+1; K=256 = 8 k-frags
    f16x8 afr[2][8];
#pragma unroll
    for (int mf = 0; mf < 2; mf++) {
        int row = mb * 128 + (wave * 2 + mf) * 16 + l15;
        const __half* ap = A + (size_t)row * 256 + q * 8;
#pragma unroll
        for (int kf = 0; kf < 8; kf++) afr[mf][kf] = *(const f16x8*)(ap + kf * 32);
    }
    f32x4 acc[2][8];
#pragma unroll
    for (int mf = 0; mf < 2; mf++)
#pragma unroll
        for (int nf = 0; nf < 8; nf++) acc[mf][nf] = (f32x4){0.f, 0.f, 0.f, 0.f};

#pragma unroll
    for (int kc = 0; kc < 2; kc++) {
        // stage B chunk [128 n][128 k] into LDS
#pragma unroll
        for (int i = 0; i < 8; i++) {
            int idx = i * 256 + tid;
            int r = idx >> 4, c = idx & 15;
            *(f16x8*)(Bs + r * KP + c * 8) =
                *(const f16x8*)(Bw + (size_t)(nb * 128 + r) * 256 + kc * 128 + c * 8);
        }
        __syncthreads();
#pragma unroll
        for (int kf = 0; kf < 4; kf++) {
#pragma unroll
            for (int nf = 0; nf < 8; nf++) {
                f16x8 bfr = *(const f16x8*)(Bs + (nf * 16 + l15) * KP + kf * 32 + q * 8);
                acc[0][nf] = __builtin_amdgcn_mfma_f32_16x16x32_f16(afr[0][kc * 4 + kf], bfr, acc[0][nf], 0, 0, 0);
                acc[1][nf] = __builtin_amdgcn_mfma_f32_16x16x32_f16(afr[1][kc * 4 + kf], bfr, acc[1][nf], 0, 0, 0);
            }
        }
        __syncthreads();
    }
    // epilogue: C[row][col], row = quad*4+reg, col = lane&15 within 16x16 tile
#pragma unroll
    for (int nf = 0; nf < 8; nf++) {
        int col = nb * 128 + nf * 16 + l15;
        float bv = bias[col];
#pragma unroll
        for (int mf = 0; mf < 2; mf++) {
            int rbase = mb * 128 + (wave * 2 + mf) * 16 + q * 4;
#pragma unroll
            for (int rr = 0; rr < 4; rr++)
                out[(size_t)(rbase + rr) * VTGT + col] = acc[mf][nf][rr] + bv;
        }
    }
}

extern "C" void kernel_launch(void* const* d_in, const int* in_sizes, int n_in,
                              void* d_out, int out_size, void* d_ws, size_t ws_size,
                              hipStream_t stream)
{
    const int*   src     = (const int*)d_in[0];
    const int*   trg     = (const int*)d_in[1];
    const float* enc_emb = (const float*)d_in[2];
    const float* enc_Wih = (const float*)d_in[3];
    const float* enc_Whh = (const float*)d_in[4];
    const float* enc_bih = (const float*)d_in[5];
    const float* enc_bhh = (const float*)d_in[6];
    const float* dec_emb = (const float*)d_in[7];
    const float* dec_Wih = (const float*)d_in[8];
    const float* dec_Whh = (const float*)d_in[9];
    const float* dec_bih = (const float*)d_in[10];
    const float* dec_bhh = (const float*)d_in[11];
    const float* fc_W    = (const float*)d_in[12];
    const float* fc_b    = (const float*)d_in[13];
    float* out = (float*)d_out;

    char* ws = (char*)d_ws;
    float*  xgE    = (float*)(ws + 0);          //  9,437,184 B
    float*  xgD    = (float*)(ws + 9437184);    //  6,291,456 B
    __half* WhhE16 = (__half*)(ws + 15728640);  //    393,216 B
    __half* WhhD16 = (__half*)(ws + 16121856);  //    393,216 B
    __half* fcW16  = (__half*)(ws + 16515072);  // 16,384,000 B
    __half* dech   = (__half*)(ws + 32899072);  //  1,048,576 B  (total ~34 MB)

    // pack weights to fp16
    pack_f16_v4<<<(49152 + 255) / 256, 256, 0, stream>>>((const float4*)enc_Whh, (f16x4*)WhhE16, 49152);
    pack_f16_v4<<<(49152 + 255) / 256, 256, 0, stream>>>((const float4*)dec_Whh, (f16x4*)WhhD16, 49152);
    pack_f16_v4<<<(2048000 + 255) / 256, 256, 0, stream>>>((const float4*)fc_W, (f16x4*)fcW16, 2048000);

    // gate-input GEMMs (fp32)
    xg_kernel<<<320, 256, 0, stream>>>(src, trg, enc_emb, enc_Wih, enc_bih,
                                       dec_emb, dec_Wih, dec_bih, xgE, xgD);

    // sequential GRU recurrence (encoder 48 steps -> decoder 32 steps)
    gru_kernel<<<64, 256, 0, stream>>>(WhhE16, enc_bhh, xgE, WhhD16, dec_bhh, xgD, dech);

    // final projection to vocab
    fc_kernel<<<dim3(250, 16), 256, 0, stream>>>(dech, fcW16, fc_b, out);
}

// Round 2
// 740.756 us; speedup vs baseline: 1.8584x; 1.8584x over previous
//
#include <hip/hip_runtime.h>
#include <hip/hip_fp16.h>

#define VTGT 32000
#define EDIM 256
#define HDIM 256
#define BATCH 64
#define SLEN 48
#define TLEN 32
#define G3 768

typedef _Float16 f16x2 __attribute__((ext_vector_type(2)));
typedef _Float16 f16x4 __attribute__((ext_vector_type(4)));
typedef _Float16 f16x8 __attribute__((ext_vector_type(8)));
typedef float    f32x4 __attribute__((ext_vector_type(4)));

__device__ __forceinline__ float sigf(float x) { return 1.f / (1.f + __expf(-x)); }
__device__ __forceinline__ float tanhfast(float x) {
    x = fminf(15.f, fmaxf(-15.f, x));
    float e = __expf(2.f * x);
    return (e - 1.f) / (e + 1.f);
}

// ---------------- pack fp32 -> fp16 (vectorized x4) ----------------
__global__ void pack_f16_v4(const float4* __restrict__ s, f16x4* __restrict__ d, int n4) {
    int i = blockIdx.x * blockDim.x + threadIdx.x;
    if (i < n4) {
        float4 v = s[i];
        f16x4 o;
        o[0] = (_Float16)v.x; o[1] = (_Float16)v.y;
        o[2] = (_Float16)v.z; o[3] = (_Float16)v.w;
        d[i] = o;
    }
}

// ---------------- xg = emb[tok] @ Wih^T + bih (fp32) ----------------
// 320 blocks: 0..191 encoder (3072 rows), 192..319 decoder (2048 rows). 16 rows/block.
__global__ __launch_bounds__(256) void xg_kernel(
    const int* __restrict__ src, const int* __restrict__ trg,
    const float* __restrict__ eemb, const float* __restrict__ eWih, const float* __restrict__ ebih,
    const float* __restrict__ demb, const float* __restrict__ dWih, const float* __restrict__ dbih,
    float* __restrict__ xgE, float* __restrict__ xgD)
{
    __shared__ __align__(16) float es[16][EDIM];
    __shared__ int toks[16];
    const int t = threadIdx.x;
    const int blk = blockIdx.x;
    const bool enc = blk < 192;
    const int row0 = enc ? blk * 16 : (blk - 192) * 16;
    if (t < 16) {
        int r = row0 + t;
        int tok;
        if (enc) { int bb = r / SLEN, tt = r % SLEN; tok = src[bb * SLEN + tt]; }
        else     { int bb = r / TLEN, tt = r % TLEN; tok = (tt == 0) ? 1 : trg[bb * TLEN + tt - 1]; }
        toks[t] = tok;
    }
    __syncthreads();
    const float* emb = enc ? eemb : demb;
    const float* Wih = enc ? eWih : dWih;
    const float* bih = enc ? ebih : dbih;
    float* outp = enc ? xgE : xgD;

    for (int i = 0; i < 4; i++) {
        int idx = i * 256 + t;
        int r = idx >> 6, c4 = idx & 63;
        ((float4*)es[r])[c4] = ((const float4*)(emb + (size_t)toks[r] * EDIM))[c4];
    }
    __syncthreads();

    float acc0[16], acc1[16], acc2[16];
#pragma unroll
    for (int r = 0; r < 16; r++) { acc0[r] = 0.f; acc1[r] = 0.f; acc2[r] = 0.f; }
    const float4* w0 = (const float4*)(Wih + (size_t)t * EDIM);
    const float4* w1 = (const float4*)(Wih + (size_t)(t + 256) * EDIM);
    const float4* w2 = (const float4*)(Wih + (size_t)(t + 512) * EDIM);
    for (int e4 = 0; e4 < 64; e4++) {
        float4 a = w0[e4], bq = w1[e4], c = w2[e4];
#pragma unroll
        for (int r = 0; r < 16; r++) {
            float4 hv = ((const float4*)es[r])[e4];
            acc0[r] += a.x * hv.x + a.y * hv.y + a.z * hv.z + a.w * hv.w;
            acc1[r] += bq.x * hv.x + bq.y * hv.y + bq.z * hv.z + bq.w * hv.w;
            acc2[r] += c.x * hv.x + c.y * hv.y + c.z * hv.z + c.w * hv.w;
        }
    }
    float b0 = bih[t], b1 = bih[t + 256], b2 = bih[t + 512];
    for (int r = 0; r < 16; r++) {
        size_t o = (size_t)(row0 + r) * G3;
        outp[o + t]       = acc0[r] + b0;
        outp[o + t + 256] = acc1[r] + b1;
        outp[o + t + 512] = acc2[r] + b2;
    }
}

// ---------------- fp16 dot helpers ----------------
__device__ __forceinline__ float dot16(f16x8 w, f16x8 hv, float acc) {
    union { f16x8 v; f16x2 h2[4]; } uw, uh;
    uw.v = w; uh.v = hv;
#if __has_builtin(__builtin_amdgcn_fdot2)
#pragma unroll
    for (int i = 0; i < 4; i++)
        acc = __builtin_amdgcn_fdot2(uw.h2[i], uh.h2[i], acc, false);
#else
#pragma unroll
    for (int i = 0; i < 4; i++) {
        acc += (float)uw.h2[i][0] * (float)uh.h2[i][0];
        acc += (float)uw.h2[i][1] * (float)uh.h2[i][1];
    }
#endif
    return acc;
}

// ---------------- GRU recurrence: 64 blocks (one batch element each) ----------------
// Whh register-resident per phase (3 rows/thread = 384 VGPRs of weights).
// h double-buffered in LDS as fp16 (1 barrier/step); gate math fp32.
__global__ __launch_bounds__(256, 1) void gru_kernel(
    const __half* __restrict__ WhhE, const float* __restrict__ bhhE, const float* __restrict__ xgE,
    const __half* __restrict__ WhhD, const float* __restrict__ bhhD, const float* __restrict__ xgD,
    __half* __restrict__ dech)
{
    __shared__ __align__(16) __half hbuf[2][HDIM];
    const int b = blockIdx.x, j = threadIdx.x;
    float h = 0.f;
    hbuf[0][j] = (__half)0.f;
    __syncthreads();

    f16x8 wr[32], wz[32], wn[32];

    // ---------------- encoder phase ----------------
    {
        const f16x8* pr = (const f16x8*)(WhhE + (size_t)j * HDIM);
        const f16x8* pz = (const f16x8*)(WhhE + (size_t)(j + 256) * HDIM);
        const f16x8* pn = (const f16x8*)(WhhE + (size_t)(j + 512) * HDIM);
#pragma unroll
        for (int k = 0; k < 32; k++) { wr[k] = pr[k]; wz[k] = pz[k]; wn[k] = pn[k]; }
        const float bR = bhhE[j], bZ = bhhE[j + 256], bN = bhhE[j + 512];
        const float* xg = xgE + (size_t)b * SLEN * G3;
        for (int t = 0; t < SLEN; t++) {
            float xr = xg[j], xz = xg[j + 256], xn = xg[j + 512];
            const f16x8* hp = (const f16x8*)hbuf[t & 1];
            float a0 = 0.f, a1 = 0.f, a2 = 0.f;
#pragma unroll
            for (int k = 0; k < 32; k++) {
                f16x8 hv = hp[k];
                a0 = dot16(wr[k], hv, a0);
                a1 = dot16(wz[k], hv, a1);
                a2 = dot16(wn[k], hv, a2);
            }
            float r = sigf(xr + a0 + bR);
            float z = sigf(xz + a1 + bZ);
            float n = tanhfast(xn + r * (a2 + bN));
            h = (1.f - z) * n + z * h;
            hbuf[(t & 1) ^ 1][j] = (__half)h;
            xg += G3;
            __syncthreads();
        }
    }
    // after t=47 the new h sits in hbuf[0]; decoder t=0 reads hbuf[0] -- parity works out.

    // ---------------- decoder phase ----------------
    {
        const f16x8* pr = (const f16x8*)(WhhD + (size_t)j * HDIM);
        const f16x8* pz = (const f16x8*)(WhhD + (size_t)(j + 256) * HDIM);
        const f16x8* pn = (const f16x8*)(WhhD + (size_t)(j + 512) * HDIM);
#pragma unroll
        for (int k = 0; k < 32; k++) { wr[k] = pr[k]; wz[k] = pz[k]; wn[k] = pn[k]; }
        const float bR = bhhD[j], bZ = bhhD[j + 256], bN = bhhD[j + 512];
        const float* xg = xgD + (size_t)b * TLEN * G3;
        __half* dptr = dech + (size_t)b * TLEN * HDIM + j;
        for (int t = 0; t < TLEN; t++) {
            float xr = xg[j], xz = xg[j + 256], xn = xg[j + 512];
            const f16x8* hp = (const f16x8*)hbuf[t & 1];
            float a0 = 0.f, a1 = 0.f, a2 = 0.f;
#pragma unroll
            for (int k = 0; k < 32; k++) {
                f16x8 hv = hp[k];
                a0 = dot16(wr[k], hv, a0);
                a1 = dot16(wz[k], hv, a1);
                a2 = dot16(wn[k], hv, a2);
            }
            float r = sigf(xr + a0 + bR);
            float z = sigf(xz + a1 + bZ);
            float n = tanhfast(xn + r * (a2 + bN));
            h = (1.f - z) * n + z * h;
            __half hh = (__half)h;
            hbuf[(t & 1) ^ 1][j] = hh;
            dptr[(size_t)t * HDIM] = hh;
            xg += G3;
            __syncthreads();
        }
    }
}

// ---------------- FC: [2048,256] x [256,32000] fp16 MFMA, fp32 accum + bias ----------------
#define KP 136  // LDS pitch in halfs (16B-aligned rows, bank step 4 -> conflict-free-ish)
__global__ __launch_bounds__(256) void fc_kernel(
    const __half* __restrict__ A, const __half* __restrict__ Bw,
    const float* __restrict__ bias, float* __restrict__ out)
{
    __shared__ __align__(16) __half Bs[128 * KP];
    const int nb = blockIdx.x;  // 0..249, 128 vocab cols
    const int mb = blockIdx.y;  // 0..15, 128 rows
    const int tid = threadIdx.x;
    const int wave = tid >> 6, lane = tid & 63;
    const int l15 = lane & 15, q = lane >> 4;

    // A fragments in registers: wave handles m-frags 2*wave, 2*wave+1; K=256 = 8 k-frags
    f16x8 afr[2][8];
#pragma unroll
    for (int mf = 0; mf < 2; mf++) {
        int row = mb * 128 + (wave * 2 + mf) * 16 + l15;
        const __half* ap = A + (size_t)row * 256 + q * 8;
#pragma unroll
        for (int kf = 0; kf < 8; kf++) afr[mf][kf] = *(const f16x8*)(ap + kf * 32);
    }
    f32x4 acc[2][8];
#pragma unroll
    for (int mf = 0; mf < 2; mf++)
#pragma unroll
        for (int nf = 0; nf < 8; nf++) acc[mf][nf] = (f32x4){0.f, 0.f, 0.f, 0.f};

#pragma unroll
    for (int kc = 0; kc < 2; kc++) {
        // stage B chunk [128 n][128 k] into LDS
#pragma unroll
        for (int i = 0; i < 8; i++) {
            int idx = i * 256 + tid;
            int r = idx >> 4, c = idx & 15;
            *(f16x8*)(Bs + r * KP + c * 8) =
                *(const f16x8*)(Bw + (size_t)(nb * 128 + r) * 256 + kc * 128 + c * 8);
        }
        __syncthreads();
#pragma unroll
        for (int kf = 0; kf < 4; kf++) {
#pragma unroll
            for (int nf = 0; nf < 8; nf++) {
                f16x8 bfr = *(const f16x8*)(Bs + (nf * 16 + l15) * KP + kf * 32 + q * 8);
                acc[0][nf] = __builtin_amdgcn_mfma_f32_16x16x32_f16(afr[0][kc * 4 + kf], bfr, acc[0][nf], 0, 0, 0);
                acc[1][nf] = __builtin_amdgcn_mfma_f32_16x16x32_f16(afr[1][kc * 4 + kf], bfr, acc[1][nf], 0, 0, 0);
            }
        }
        __syncthreads();
    }
    // epilogue: C[row][col], row = quad*4+reg, col = lane&15 within 16x16 tile
#pragma unroll
    for (int nf = 0; nf < 8; nf++) {
        int col = nb * 128 + nf * 16 + l15;
        float bv = bias[col];
#pragma unroll
        for (int mf = 0; mf < 2; mf++) {
            int rbase = mb * 128 + (wave * 2 + mf) * 16 + q * 4;
#pragma unroll
            for (int rr = 0; rr < 4; rr++)
                out[(size_t)(rbase + rr) * VTGT + col] = acc[mf][nf][rr] + bv;
        }
    }
}

extern "C" void kernel_launch(void* const* d_in, const int* in_sizes, int n_in,
                              void* d_out, int out_size, void* d_ws, size_t ws_size,
                              hipStream_t stream)
{
    const int*   src     = (const int*)d_in[0];
    const int*   trg     = (const int*)d_in[1];
    const float* enc_emb = (const float*)d_in[2];
    const float* enc_Wih = (const float*)d_in[3];
    const float* enc_Whh = (const float*)d_in[4];
    const float* enc_bih = (const float*)d_in[5];
    const float* enc_bhh = (const float*)d_in[6];
    const float* dec_emb = (const float*)d_in[7];
    const float* dec_Wih = (const float*)d_in[8];
    const float* dec_Whh = (const float*)d_in[9];
    const float* dec_bih = (const float*)d_in[10];
    const float* dec_bhh = (const float*)d_in[11];
    const float* fc_W    = (const float*)d_in[12];
    const float* fc_b    = (const float*)d_in[13];
    float* out = (float*)d_out;

    char* ws = (char*)d_ws;
    float*  xgE    = (float*)(ws + 0);          //  9,437,184 B
    float*  xgD    = (float*)(ws + 9437184);    //  6,291,456 B
    __half* WhhE16 = (__half*)(ws + 15728640);  //    393,216 B
    __half* WhhD16 = (__half*)(ws + 16121856);  //    393,216 B
    __half* fcW16  = (__half*)(ws + 16515072);  // 16,384,000 B
    __half* dech   = (__half*)(ws + 32899072);  //  1,048,576 B  (total ~34 MB)

    // pack weights to fp16
    pack_f16_v4<<<(49152 + 255) / 256, 256, 0, stream>>>((const float4*)enc_Whh, (f16x4*)WhhE16, 49152);
    pack_f16_v4<<<(49152 + 255) / 256, 256, 0, stream>>>((const float4*)dec_Whh, (f16x4*)WhhD16, 49152);
    pack_f16_v4<<<(2048000 + 255) / 256, 256, 0, stream>>>((const float4*)fc_W, (f16x4*)fcW16, 2048000);

    // gate-input GEMMs (fp32)
    xg_kernel<<<320, 256, 0, stream>>>(src, trg, enc_emb, enc_Wih, enc_bih,
                                       dec_emb, dec_Wih, dec_bih, xgE, xgD);

    // sequential GRU recurrence (encoder 48 steps -> decoder 32 steps)
    gru_kernel<<<64, 256, 0, stream>>>(WhhE16, enc_bhh, xgE, WhhD16, dec_bhh, xgD, dech);

    // final projection to vocab
    fc_kernel<<<dim3(250, 16), 256, 0, stream>>>(dech, fcW16, fc_b, out);
}